// Round 3
// baseline (766.469 us; speedup 1.0000x reference)
//
#include <hip/hip_runtime.h>

typedef short short8 __attribute__((ext_vector_type(8)));
typedef float f32x4 __attribute__((ext_vector_type(4)));

#define XP_BYTES (16ull * 130 * 130 * 128 * 2)

static __device__ __forceinline__ unsigned short f2bf(float f) {
  unsigned u = __float_as_uint(f);
  u += 0x7FFFu + ((u >> 16) & 1u);
  return (unsigned short)(u >> 16);
}

static __device__ __forceinline__ void gload16(const void* g, void* l) {
  __builtin_amdgcn_global_load_lds(
      (const __attribute__((address_space(1))) void*)g,
      (__attribute__((address_space(3))) void*)l, 16, 0, 0);
}

// ---------------- weight rotation: (O*R,I,3,3) fp32 -> W2[n'=o*8+r][tap*128+ic] bf16
static __device__ __forceinline__ float wtap(const float* f, int yi, int xi) {
  bool valid = (yi >= 0) & (yi < 3) & (xi >= 0) & (xi < 3);
  int yc = min(max(yi, 0), 2), xc = min(max(xi, 0), 2);
  return valid ? f[yc * 3 + xc] : 0.f;
}

__global__ __launch_bounds__(256) void wprep_kernel(
    const float* __restrict__ w, const float* __restrict__ rot_alpha,
    unsigned short* __restrict__ w2) {
  int gid = blockIdx.x * 256 + threadIdx.x;  // 131072 = 1024 * 128
  int ic = gid & 127;
  int nr = gid >> 7;  // n' = o*8 + r
  int r = nr & 7;
  const float* wf = w + (size_t)nr * (128 * 9) + (size_t)ic * 9;
  float f[9];
#pragma unroll
  for (int q = 0; q < 9; ++q) f[q] = wf[q];
  float ang = rot_alpha[r] * 0.78539816339744830962f * (float)r;
  float sth, cth;
  sincosf(ang, &sth, &cth);
#pragma unroll
  for (int j = 0; j < 3; ++j) {
#pragma unroll
    for (int i = 0; i < 3; ++i) {
      float gy = (float)(j - 1), gx = (float)(i - 1);
      float xs = cth * gx - sth * gy;
      float ys = sth * gx + cth * gy;
      float ix = xs + 1.0f, iy = ys + 1.0f;
      float x0f = floorf(ix), y0f = floorf(iy);
      int x0 = (int)x0f, y0 = (int)y0f;
      float wx = ix - x0f, wy = iy - y0f;
      float acc = wtap(f, y0, x0) * (1.f - wy) * (1.f - wx)
                + wtap(f, y0, x0 + 1) * (1.f - wy) * wx
                + wtap(f, y0 + 1, x0) * wy * (1.f - wx)
                + wtap(f, y0 + 1, x0 + 1) * wy * wx;
      w2[(size_t)nr * 1152 + (size_t)(j * 3 + i) * 128 + ic] = f2bf(acc);
    }
  }
}

// ---------------- x: NCHW fp32 -> padded NHWC bf16 xp[16][130][130][128]
__global__ __launch_bounds__(256) void xprep_kernel(
    const float* __restrict__ x, unsigned short* __restrict__ xp) {
  const int yy = blockIdx.x;  // 0..129
  const int b = blockIdx.y;   // 0..15
  const int t = threadIdx.x;
  const size_t rowbase = ((size_t)b * 130 + yy) * (130 * 128);
  if (yy == 0 || yy == 129) {
    uint4 z = {0u, 0u, 0u, 0u};
    for (int i = t; i < 2080; i += 256)
      ((uint4*)(xp + rowbase))[i] = z;
    return;
  }
  const int y = yy - 1;
  __shared__ float lt[32][129];
  if (t < 32) {
    uint4 z = {0u, 0u, 0u, 0u};
    int xx = (t < 16) ? 0 : 129;
    int cc = (t & 15) * 8;
    *(uint4*)(xp + rowbase + (size_t)xx * 128 + cc) = z;
  }
  for (int c0 = 0; c0 < 128; c0 += 32) {
#pragma unroll
    for (int i = 0; i < 16; ++i) {
      int idx = i * 256 + t;
      int c = idx >> 7, wq = idx & 127;
      lt[c][wq] = x[(((size_t)b * 128 + c0 + c) * 128 + y) * 128 + wq];
    }
    __syncthreads();
#pragma unroll
    for (int i = 0; i < 2; ++i) {
      int u = i * 256 + t;
      int xx = u >> 2, cp = (u & 3) * 8;
      unsigned short v[8];
#pragma unroll
      for (int q = 0; q < 8; ++q) v[q] = f2bf(lt[cp + q][xx]);
      *(uint4*)(xp + rowbase + (size_t)(xx + 1) * 128 + c0 + cp) = *(uint4*)v;
    }
    __syncthreads();
  }
}

// ---------------- implicit-GEMM conv, 256x256 tile, BK=64, 8 waves, m201-style
// 8-phase schedule: 4 phases/K-tile (kk x mh), 16 MFMA/phase, counted vmcnt(4).
// LDS layout: A[2buf][2hp][2kk][128 rows][32k] + B same = 128 KiB.
// Read swizzle: slot ^= (l15>>1)&3 ; staging source pre-applies the inverse.
__global__ __launch_bounds__(512, 2) void conv_kernel(
    const unsigned short* __restrict__ xp,
    const unsigned short* __restrict__ w2,
    float* __restrict__ out) {
  __shared__ unsigned short lds[65536];  // 128 KiB

  const int tid = threadIdx.x;
  const int lane = tid & 63;
  const int wv = tid >> 6;  // 0..7
  const int wr = wv >> 2;   // M half
  const int wc = wv & 3;    // N quarter

  const int bid = blockIdx.x;
  const int wg = (bid & 7) * 512 + (bid >> 3);  // XCD swizzle (4096 % 8 == 0)
  const int mblk = wg >> 2;
  const int nblk = wg & 3;
  const int b = mblk >> 6;
  const int y0 = (mblk & 63) << 1;

  // staging decode: thread t covers row r0, lds slot s0 (16B slots of 4/row)
  const int r0 = tid >> 2;
  const int s0 = tid & 3;
  const int g0 = s0 ^ ((r0 >> 1) & 3);  // global k-group (inverse swizzle)
  const int wvoff = wv * 512;           // shorts: wave's linear chunk base

  const unsigned short* xpt =
      xp + (size_t)(b * 130 + y0) * 130 * 128 + r0 * 128 + g0 * 8;
  const unsigned short* wpt =
      w2 + (size_t)nblk * 256 * 1152 + (size_t)r0 * 1152 + g0 * 8;

  const int l15 = lane & 15;
  const int lhi = lane >> 4;
  const int sa = (lhi ^ ((l15 >> 1) & 3)) * 8;  // read-side swizzled slot

  const int aRd = wr * 8192 + l15 * 32 + sa;                       // shorts
  const int bRd = 32768 + (wc >> 1) * 8192 + (wc & 1) * 2048 + l15 * 32 + sa;

  f32x4 acc[8][4];
#pragma unroll
  for (int mf = 0; mf < 8; ++mf)
#pragma unroll
    for (int nf = 0; nf < 4; ++nf) acc[mf][nf] = (f32x4){0.f, 0.f, 0.f, 0.f};

#define STAGE_A(BUF, HP, KK, DY, DX, CH)                                     \
  gload16(xpt + ((HP + DY) * 130 + DX) * 128 + (CH) * 64 + (KK) * 32,        \
          lds + (BUF) * 16384 + (HP) * 8192 + (KK) * 4096 + wvoff)
#define STAGE_B(BUF, HN, KK, TAP, CH)                                        \
  gload16(wpt + (size_t)(HN) * 147456 + (TAP) * 128 + (CH) * 64 + (KK) * 32, \
          lds + 32768 + (BUF) * 16384 + (HN) * 8192 + (KK) * 4096 + wvoff)

  // ---- prologue: stage tile 0 (tap=0, chalf=0), kk0 first
  STAGE_A(0, 0, 0, 0, 0, 0);
  STAGE_A(0, 1, 0, 0, 0, 0);
  STAGE_B(0, 0, 0, 0, 0);
  STAGE_B(0, 1, 0, 0, 0);
  STAGE_A(0, 0, 1, 0, 0, 0);
  STAGE_A(0, 1, 1, 0, 0, 0);
  STAGE_B(0, 0, 1, 0, 0);
  STAGE_B(0, 1, 1, 0, 0);
  asm volatile("s_waitcnt vmcnt(4)" ::: "memory");
  __builtin_amdgcn_s_barrier();

#pragma unroll 2
  for (int kt = 0; kt < 18; ++kt) {
    const int buf = kt & 1;
    const bool st = kt < 17;
    const int nt = kt + 1;
    const int ntap = nt >> 1;
    const int nch = nt & 1;
    const int nbuf = nt & 1;
    const int ndy = ntap / 3;
    const int ndx = ntap - ndy * 3;

    const unsigned short* pA = lds + buf * 16384 + aRd;
    const unsigned short* pB = lds + buf * 16384 + bRd;
    short8 af[4], bf[4];

    // ===== phase 0: kk=0, mh=0 =====
#pragma unroll
    for (int q = 0; q < 4; ++q) af[q] = *(const short8*)(pA + q * 512);
#pragma unroll
    for (int nf = 0; nf < 4; ++nf) bf[nf] = *(const short8*)(pB + nf * 512);
    if (st) { STAGE_A(nbuf, 0, 0, ndy, ndx, nch); STAGE_A(nbuf, 1, 0, ndy, ndx, nch); }
    __builtin_amdgcn_s_barrier();
    asm volatile("s_waitcnt lgkmcnt(0)" ::: "memory");
    __builtin_amdgcn_s_setprio(1);
#pragma unroll
    for (int q = 0; q < 4; ++q)
#pragma unroll
      for (int nf = 0; nf < 4; ++nf)
        acc[q][nf] = __builtin_amdgcn_mfma_f32_16x16x32_bf16(af[q], bf[nf],
                                                             acc[q][nf], 0, 0, 0);
    __builtin_amdgcn_s_setprio(0);
    __builtin_amdgcn_s_barrier();

    // ===== phase 1: kk=0, mh=1 =====
#pragma unroll
    for (int q = 0; q < 4; ++q) af[q] = *(const short8*)(pA + 2048 + q * 512);
    if (st) { STAGE_B(nbuf, 0, 0, ntap, nch); STAGE_B(nbuf, 1, 0, ntap, nch); }
    if (st) asm volatile("s_waitcnt vmcnt(4)" ::: "memory");
    else    asm volatile("s_waitcnt vmcnt(0)" ::: "memory");
    __builtin_amdgcn_s_barrier();
    asm volatile("s_waitcnt lgkmcnt(0)" ::: "memory");
    __builtin_amdgcn_s_setprio(1);
#pragma unroll
    for (int q = 0; q < 4; ++q)
#pragma unroll
      for (int nf = 0; nf < 4; ++nf)
        acc[4 + q][nf] = __builtin_amdgcn_mfma_f32_16x16x32_bf16(
            af[q], bf[nf], acc[4 + q][nf], 0, 0, 0);
    __builtin_amdgcn_s_setprio(0);
    __builtin_amdgcn_s_barrier();

    // ===== phase 2: kk=1, mh=0 =====
#pragma unroll
    for (int q = 0; q < 4; ++q) af[q] = *(const short8*)(pA + 4096 + q * 512);
#pragma unroll
    for (int nf = 0; nf < 4; ++nf) bf[nf] = *(const short8*)(pB + 4096 + nf * 512);
    if (st) { STAGE_A(nbuf, 0, 1, ndy, ndx, nch); STAGE_A(nbuf, 1, 1, ndy, ndx, nch); }
    __builtin_amdgcn_s_barrier();
    asm volatile("s_waitcnt lgkmcnt(0)" ::: "memory");
    __builtin_amdgcn_s_setprio(1);
#pragma unroll
    for (int q = 0; q < 4; ++q)
#pragma unroll
      for (int nf = 0; nf < 4; ++nf)
        acc[q][nf] = __builtin_amdgcn_mfma_f32_16x16x32_bf16(af[q], bf[nf],
                                                             acc[q][nf], 0, 0, 0);
    __builtin_amdgcn_s_setprio(0);
    __builtin_amdgcn_s_barrier();

    // ===== phase 3: kk=1, mh=1 =====
#pragma unroll
    for (int q = 0; q < 4; ++q)
      af[q] = *(const short8*)(pA + 4096 + 2048 + q * 512);
    if (st) { STAGE_B(nbuf, 0, 1, ntap, nch); STAGE_B(nbuf, 1, 1, ntap, nch); }
    if (st) asm volatile("s_waitcnt vmcnt(4)" ::: "memory");
    else    asm volatile("s_waitcnt vmcnt(0)" ::: "memory");
    __builtin_amdgcn_s_barrier();
    asm volatile("s_waitcnt lgkmcnt(0)" ::: "memory");
    __builtin_amdgcn_s_setprio(1);
#pragma unroll
    for (int q = 0; q < 4; ++q)
#pragma unroll
      for (int nf = 0; nf < 4; ++nf)
        acc[4 + q][nf] = __builtin_amdgcn_mfma_f32_16x16x32_bf16(
            af[q], bf[nf], acc[4 + q][nf], 0, 0, 0);
    __builtin_amdgcn_s_setprio(0);
    __builtin_amdgcn_s_barrier();
  }
#undef STAGE_A
#undef STAGE_B

  // ---- epilogue: max over 8 rotations (8 adjacent n' cols), coalesced store
  float* lE = (float*)lds;  // [256 pix][33] fp32
#pragma unroll
  for (int mf = 0; mf < 8; ++mf)
#pragma unroll
    for (int nf = 0; nf < 4; ++nf)
#pragma unroll
      for (int j = 0; j < 4; ++j) {
        float v = acc[mf][nf][j];
        v = fmaxf(v, __shfl_xor(v, 1, 64));
        v = fmaxf(v, __shfl_xor(v, 2, 64));
        v = fmaxf(v, __shfl_xor(v, 4, 64));
        if ((lane & 7) == 0) {
          int pix = wr * 128 + mf * 16 + lhi * 4 + j;
          int ol = wc * 8 + nf * 2 + ((lane >> 3) & 1);
          lE[pix * 33 + ol] = v;
        }
      }
  __syncthreads();
  const size_t obase = ((size_t)(b * 128 + nblk * 32) * 128 + y0) * 128;
#pragma unroll
  for (int i = 0; i < 16; ++i) {
    int idx = i * 512 + tid;
    int ol = idx >> 8;
    int pix = idx & 255;
    int yl = pix >> 7;
    int xx = pix & 127;
    out[obase + (size_t)ol * 16384 + yl * 128 + xx] = lE[pix * 33 + ol];
  }
}

extern "C" void kernel_launch(void* const* d_in, const int* in_sizes, int n_in,
                              void* d_out, int out_size, void* d_ws, size_t ws_size,
                              hipStream_t stream) {
  const float* x = (const float*)d_in[0];
  const float* w = (const float*)d_in[1];
  const float* ra = (const float*)d_in[2];
  float* out = (float*)d_out;
  unsigned short* xp = (unsigned short*)d_ws;
  unsigned short* w2 = (unsigned short*)((char*)d_ws + XP_BYTES);

  hipLaunchKernelGGL(wprep_kernel, dim3(512), dim3(256), 0, stream, w, ra, w2);
  hipLaunchKernelGGL(xprep_kernel, dim3(130, 16), dim3(256), 0, stream, x, xp);
  hipLaunchKernelGGL(conv_kernel, dim3(4096), dim3(512), 0, stream, xp, w2, out);
}